// Round 2
// baseline (193.401 us; speedup 1.0000x reference)
//
#include <hip/hip_runtime.h>

// tanh(x) = 1 - 2/(exp(2x)+1), using hw v_exp_f32 (computes 2^x) and v_rcp_f32.
// Saturates correctly: x->+inf => e=inf => rcp=0 => 1; x->-inf => e=0 => -1.
__device__ __forceinline__ float fast_tanh(float x) {
    // exp(2x) = 2^(2x * log2(e)) = exp2(x * 2.8853900817779268f)
    float e = __builtin_amdgcn_exp2f(x * 2.8853900817779268f);
    float r = __builtin_amdgcn_rcpf(e + 1.0f);
    return 1.0f - 2.0f * r;
}

__global__ __launch_bounds__(256) void rnn2_cls_kernel(
    const float* __restrict__ X,       // [B,4,2]
    const float* __restrict__ w_ih,    // [2,2] row-major: w_ih[h*2+d]
    const float* __restrict__ b_ih,    // [2]
    const float* __restrict__ w_hh,    // [2,2]
    const float* __restrict__ b_hh,    // [2]
    const float* __restrict__ cls_w,   // [1,2]
    const float* __restrict__ cls_b,   // [1]
    float* __restrict__ out,           // [B]
    int B)
{
    int b = blockIdx.x * blockDim.x + threadIdx.x;
    if (b >= B) return;

    // Uniform-address parameter loads: L1-broadcast, negligible HBM traffic.
    const float w00 = w_ih[0], w01 = w_ih[1], w10 = w_ih[2], w11 = w_ih[3];
    const float bi0 = b_ih[0], bi1 = b_ih[1];
    const float u00 = w_hh[0], u01 = w_hh[1], u10 = w_hh[2], u11 = w_hh[3];
    const float bh0 = b_hh[0], bh1 = b_hh[1];
    const float c0 = cls_w[0], c1 = cls_w[1], cb = cls_b[0];

    // 32 B/lane via two float4 loads — coalesced.
    const float4* X4 = reinterpret_cast<const float4*>(X);
    float4 lo = X4[2 * b];
    float4 hi = X4[2 * b + 1];
    float x[8] = {lo.x, lo.y, lo.z, lo.w, hi.x, hi.y, hi.z, hi.w};

    float h0 = 0.0f, h1 = 0.0f;
#pragma unroll
    for (int t = 0; t < 4; ++t) {
        float xt0 = x[2 * t], xt1 = x[2 * t + 1];
        // ix_t[h] = W_ih[h][0]*x0 + W_ih[h][1]*x1 + b_ih[h]
        float p0 = fmaf(w00, xt0, fmaf(w01, xt1, bi0));
        float p1 = fmaf(w10, xt0, fmaf(w11, xt1, bi1));
        // h_t[h] = tanh(ix_t[h] + W_hh[h][0]*h0 + W_hh[h][1]*h1 + b_hh[h])
        float n0 = fast_tanh(p0 + fmaf(u00, h0, fmaf(u01, h1, bh0)));
        float n1 = fast_tanh(p1 + fmaf(u10, h0, fmaf(u11, h1, bh1)));
        h0 = n0;
        h1 = n1;
    }
    out[b] = fmaf(c0, h0, fmaf(c1, h1, cb));
}

extern "C" void kernel_launch(void* const* d_in, const int* in_sizes, int n_in,
                              void* d_out, int out_size, void* d_ws, size_t ws_size,
                              hipStream_t stream) {
    const float* X     = (const float*)d_in[0];
    const float* w_ih  = (const float*)d_in[1];
    const float* b_ih  = (const float*)d_in[2];
    const float* w_hh  = (const float*)d_in[3];
    const float* b_hh  = (const float*)d_in[4];
    const float* cls_w = (const float*)d_in[5];
    const float* cls_b = (const float*)d_in[6];
    float* out = (float*)d_out;

    int B = in_sizes[0] / 8;  // X is [B,4,2]
    int block = 256;
    int grid = (B + block - 1) / block;
    rnn2_cls_kernel<<<grid, block, 0, stream>>>(X, w_ih, b_ih, w_hh, b_hh,
                                                cls_w, cls_b, out, B);
}